// Round 9
// baseline (817.381 us; speedup 1.0000x reference)
//
#include <hip/hip_runtime.h>
#include <hip/hip_cooperative_groups.h>

namespace cg = cooperative_groups;

#define NNODES 100000
#define NEDGES 625000
#define DFEAT  128
#define NGRAPH 256
#define DOUTC  10
#define NCHUNK ((NNODES + 1023) / 1024)   // 98

typedef __attribute__((ext_vector_type(8))) short bf16x8;
typedef __attribute__((ext_vector_type(4))) float f32x4;
typedef __attribute__((ext_vector_type(8))) ushort ushort8v;

__device__ __forceinline__ ushort f2bf(float f) {
    __bf16 b = (__bf16)f;
    return __builtin_bit_cast(ushort, b);
}
__device__ __forceinline__ float bf2f(ushort u) {
    return __builtin_bit_cast(float, (uint)u << 16);
}

// ---------------------------------------------------------------------------
// convert_all: weights->bf16, x->bf16, zero gsum  (one low-VGPR kernel)
// ---------------------------------------------------------------------------
__global__ __launch_bounds__(256) void convert_all(const float* __restrict__ x,
                                                   const float* __restrict__ w0,
                                                   const float* __restrict__ w1,
                                                   const float* __restrict__ w2,
                                                   const float* __restrict__ w3,
                                                   const float* __restrict__ w4,
                                                   const float* __restrict__ w5,
                                                   ushort* __restrict__ Wb,
                                                   ushort* __restrict__ Hb,
                                                   float* __restrict__ gsum) {
    const int tid = blockIdx.x * 256 + threadIdx.x;
    const int NT = gridDim.x * 256;
    const float* ptrs[6] = {w0, w1, w2, w3, w4, w5};
    for (int i = tid; i < 6 * DFEAT * DFEAT; i += NT) {
        int m = i >> 14, j = i & 16383;
        Wb[i] = f2bf(ptrs[m][j]);
    }
    for (int i = tid; i < NGRAPH * DFEAT; i += NT) gsum[i] = 0.f;
    const int n8 = NNODES * DFEAT / 8;
    for (int i = tid; i < n8; i += NT) {
        float4 a = *(const float4*)&x[(size_t)i * 8];
        float4 b = *(const float4*)&x[(size_t)i * 8 + 4];
        ushort8v o;
        o[0] = f2bf(a.x); o[1] = f2bf(a.y); o[2] = f2bf(a.z); o[3] = f2bf(a.w);
        o[4] = f2bf(b.x); o[5] = f2bf(b.y); o[6] = f2bf(b.z); o[7] = f2bf(b.w);
        *(ushort8v*)&Hb[(size_t)i * 8] = o;
    }
}

// ---------------------------------------------------------------------------
// csr_build (cooperative): zero deg -> histogram -> 3-stage scan -> scatter.
// All phases low-VGPR, full occupancy; grid.sync replaces dispatch gaps.
// ---------------------------------------------------------------------------
struct CsrP {
    const int* rows;
    const int* cols;
    int* deg;
    int* offs;
    int* cursor;
    int* scol;
    int* bsum;
    int* bbase;
};

__global__ __launch_bounds__(256) void csr_build(CsrP p) {
    cg::grid_group grid = cg::this_grid();
    const int t = threadIdx.x;
    const int b = blockIdx.x;
    const int tid = b * 256 + t;
    const int NT = gridDim.x * 256;
    __shared__ int red[256];
    __shared__ int shb[128];

    // ph0: zero deg
    for (int i = tid; i < NNODES; i += NT) p.deg[i] = 0;
    grid.sync();

    // ph1: degree histogram
    for (int i = tid; i < NEDGES; i += NT) atomicAdd(&p.deg[p.rows[i]], 1);
    grid.sync();

    // ph2a: per-chunk sums (blocks 0..NCHUNK-1, 1024 nodes each)
    if (b < NCHUNK) {
        int base = b * 1024 + t * 4;
        int s = 0;
#pragma unroll
        for (int j = 0; j < 4; ++j) {
            int i = base + j;
            if (i < NNODES) s += p.deg[i];
        }
        red[t] = s;
        __syncthreads();
        for (int off = 128; off > 0; off >>= 1) {
            if (t < off) red[t] += red[t + off];
            __syncthreads();
        }
        if (t == 0) p.bsum[b] = red[0];
    }
    grid.sync();

    // ph2b: scan chunk sums (block 0)
    if (b == 0) {
        if (t < 128) shb[t] = (t < NCHUNK) ? p.bsum[t] : 0;
        __syncthreads();
        if (t == 0) {
            int run = 0;
            for (int i = 0; i < NCHUNK; ++i) { int v = shb[i]; shb[i] = run; run += v; }
        }
        __syncthreads();
        if (t < NCHUNK) p.bbase[t] = shb[t];
    }
    grid.sync();

    // ph2c: write offs + cursor
    if (b < NCHUNK) {
        int base = b * 1024 + t * 4;
        int v[4];
        int s = 0;
#pragma unroll
        for (int j = 0; j < 4; ++j) {
            int i = base + j;
            v[j] = (i < NNODES) ? p.deg[i] : 0;
            s += v[j];
        }
        red[t] = s;
        __syncthreads();
        int x = s;
        for (int off = 1; off < 256; off <<= 1) {
            int y = (t >= off) ? red[t - off] : 0;
            __syncthreads();
            x += y;
            red[t] = x;
            __syncthreads();
        }
        int pre = p.bbase[b] + x - s;
#pragma unroll
        for (int j = 0; j < 4; ++j) {
            int i = base + j;
            if (i < NNODES) { p.offs[i] = pre; p.cursor[i] = pre; }
            pre += v[j];
        }
    }
    if (tid == 0) p.offs[NNODES] = NEDGES;
    grid.sync();

    // ph3: scatter edges
    for (int i = tid; i < NEDGES; i += NT) {
        int pos = atomicAdd(&p.cursor[p.rows[i]], 1);
        p.scol[pos] = p.cols[i];
    }
}

// ---------------------------------------------------------------------------
// Aggregate in H-space: A[n] = sum_{e in CSR[n]} H[scol[e]]
// One 16-lane group per node (4 nodes/wave), lane owns 8 features (16 B).
// (identical to R7 — proven)
// ---------------------------------------------------------------------------
__global__ __launch_bounds__(256) void aggregate_g16(const ushort* __restrict__ Hb,
                                                     const int* __restrict__ offs,
                                                     const int* __restrict__ scol,
                                                     ushort* __restrict__ Ab) {
    int node = blockIdx.x * 16 + (threadIdx.x >> 4);
    int l = threadIdx.x & 15;
    if (node >= NNODES) return;
    int beg = offs[node];
    int end = offs[node + 1];
    float a[8] = {};
    int e = beg;
    for (; e + 2 <= end; e += 2) {
        int c0 = scol[e];
        int c1 = scol[e + 1];
        ushort8v v0 = *(const ushort8v*)&Hb[(size_t)c0 * DFEAT + l * 8];
        ushort8v v1 = *(const ushort8v*)&Hb[(size_t)c1 * DFEAT + l * 8];
#pragma unroll
        for (int j = 0; j < 8; ++j) a[j] += bf2f(v0[j]) + bf2f(v1[j]);
    }
    if (e < end) {
        int c0 = scol[e];
        ushort8v v0 = *(const ushort8v*)&Hb[(size_t)c0 * DFEAT + l * 8];
#pragma unroll
        for (int j = 0; j < 8; ++j) a[j] += bf2f(v0[j]);
    }
    ushort8v o;
#pragma unroll
    for (int j = 0; j < 8; ++j) o[j] = f2bf(a[j]);
    *(ushort8v*)&Ab[(size_t)node * DFEAT + l * 8] = o;
}

// ---------------------------------------------------------------------------
// Fused layer GEMM: H' = relu(H @ W1^T + A @ W2^T)  (identical to R7 — proven)
// ---------------------------------------------------------------------------
__global__ __launch_bounds__(256, 2) void fused_dual_gemm(const ushort* __restrict__ Hin,
                                                          const ushort* __restrict__ Ab,
                                                          const ushort* __restrict__ W1b,
                                                          const ushort* __restrict__ W2b,
                                                          ushort* __restrict__ Hout) {
    int wid = threadIdx.x >> 6;
    int lane = threadIdx.x & 63;
    int l15 = lane & 15, lhi = lane >> 4;
    int half = wid & 1;

    bf16x8 w1[4][4], w2[4][4];
#pragma unroll
    for (int ot = 0; ot < 4; ++ot)
#pragma unroll
        for (int ks = 0; ks < 4; ++ks) {
            int orow = half * 64 + ot * 16 + l15;
            w1[ot][ks] = *(const bf16x8*)&W1b[orow * DFEAT + ks * 32 + lhi * 8];
            w2[ot][ks] = *(const bf16x8*)&W2b[orow * DFEAT + ks * 32 + lhi * 8];
        }

    int team = blockIdx.x * 2 + (wid >> 1);
    const int nteams = gridDim.x * 2;
    const int ntiles = NNODES / 16;              // 6250 exactly

    for (int t = team; t < ntiles; t += nteams) {
        size_t rowOff = (size_t)(t * 16 + l15) * DFEAT;
        bf16x8 hfr[4], afr[4];
#pragma unroll
        for (int ks = 0; ks < 4; ++ks) {
            hfr[ks] = *(const bf16x8*)&Hin[rowOff + ks * 32 + lhi * 8];
            afr[ks] = *(const bf16x8*)&Ab[rowOff + ks * 32 + lhi * 8];
        }
#pragma unroll
        for (int ot = 0; ot < 4; ++ot) {
            f32x4 acc = {};
#pragma unroll
            for (int ks = 0; ks < 4; ++ks)
                acc = __builtin_amdgcn_mfma_f32_16x16x32_bf16(w1[ot][ks], hfr[ks], acc, 0, 0, 0);
#pragma unroll
            for (int ks = 0; ks < 4; ++ks)
                acc = __builtin_amdgcn_mfma_f32_16x16x32_bf16(w2[ot][ks], afr[ks], acc, 0, 0, 0);
            ushort4 p;
            p.x = f2bf(fmaxf(acc.x, 0.f));
            p.y = f2bf(fmaxf(acc.y, 0.f));
            p.z = f2bf(fmaxf(acc.z, 0.f));
            p.w = f2bf(fmaxf(acc.w, 0.f));
            *(ushort4*)&Hout[rowOff + half * 64 + ot * 16 + lhi * 4] = p;
        }
    }
}

// ---------------------------------------------------------------------------
// pool_coop (cooperative): run-accumulate partial sums, then classify.
// ---------------------------------------------------------------------------
struct PoolP {
    const ushort* H;
    const int* batch;
    float* gsum;
    const float* Wc;
    const float* bc;
    float* out;
};

__global__ __launch_bounds__(256) void pool_coop(PoolP p) {
    cg::grid_group grid = cg::this_grid();
    const int t = threadIdx.x;
    const int b = blockIdx.x;
    const int gw = (b * 256 + t) >> 6;
    const int lane = t & 63;
    __shared__ float red[256];
    __shared__ int bounds[2];

    // phase 1: per-graph feature sums (wave per 64-node chunk, sorted batch)
    int base = gw * 64;
    if (base < NNODES) {
        int end = min(base + 64, NNODES);
        const uint* Hp = (const uint*)p.H + lane;
        float ax = 0.f, ay = 0.f;
        int gprev = p.batch[base];
        for (int n = base; n < end; ++n) {
            int g = p.batch[n];
            if (g != gprev) {
                atomicAdd(&p.gsum[gprev * DFEAT + lane * 2], ax);
                atomicAdd(&p.gsum[gprev * DFEAT + lane * 2 + 1], ay);
                ax = 0.f; ay = 0.f; gprev = g;
            }
            uint v = Hp[(size_t)n * 64];
            ax += __builtin_bit_cast(float, v << 16);
            ay += __builtin_bit_cast(float, v & 0xffff0000u);
        }
        atomicAdd(&p.gsum[gprev * DFEAT + lane * 2], ax);
        atomicAdd(&p.gsum[gprev * DFEAT + lane * 2 + 1], ay);
    }
    grid.sync();

    // phase 2: classify (blocks 0..NGRAPH-1; all 256 threads sync-uniform)
    if (b < NGRAPH) {
        int g = b;
        if (t < 2) {
            int target = g + t;
            int lo = 0, hi = NNODES;
            while (lo < hi) {
                int mid = (lo + hi) >> 1;
                if (p.batch[mid] < target) lo = mid + 1; else hi = mid;
            }
            bounds[t] = lo;
        }
        __syncthreads();
        float pooled = 0.f;
        if (t < DFEAT) {
            float cnt = (float)(bounds[1] - bounds[0]);
            pooled = p.gsum[g * DFEAT + t] / fmaxf(cnt, 1.0f);
        }
        for (int o = 0; o < DOUTC; ++o) {
            red[t] = (t < DFEAT) ? pooled * p.Wc[o * DFEAT + t] : 0.f;
            __syncthreads();
            for (int off = 128; off > 0; off >>= 1) {
                if (t < off) red[t] += red[t + off];
                __syncthreads();
            }
            if (t == 0) p.out[g * DOUTC + o] = red[0] + p.bc[o];
            __syncthreads();
        }
    }
}

// ---------------------------------------------------------------------------
extern "C" void kernel_launch(void* const* d_in, const int* in_sizes, int n_in,
                              void* d_out, int out_size, void* d_ws, size_t ws_size,
                              hipStream_t stream) {
    const float* x    = (const float*)d_in[0];
    const int*   ei   = (const int*)d_in[1];
    const int*   batch= (const int*)d_in[2];
    const float* Wc   = (const float*)d_in[9];
    const float* bc   = (const float*)d_in[10];
    float* out = (float*)d_out;

    const int* rows = ei;            // edge_index[0] = dst (segment)
    const int* cols = ei + NEDGES;   // edge_index[1] = src (gather)

    // workspace carve-up
    char* ws = (char*)d_ws;
    ushort* Hb = (ushort*)ws;  ws += (size_t)NNODES * DFEAT * sizeof(ushort);
    ushort* Hc = (ushort*)ws;  ws += (size_t)NNODES * DFEAT * sizeof(ushort);
    ushort* Ab = (ushort*)ws;  ws += (size_t)NNODES * DFEAT * sizeof(ushort);
    ushort* Wb = (ushort*)ws;  ws += (size_t)6 * DFEAT * DFEAT * sizeof(ushort);
    float* gsum = (float*)ws;  ws += (size_t)NGRAPH * DFEAT * sizeof(float);
    int* deg    = (int*)ws;    ws += (size_t)NNODES * sizeof(int);
    int* offs   = (int*)ws;    ws += (size_t)(NNODES + 1) * sizeof(int);
    int* cursor = (int*)ws;    ws += (size_t)NNODES * sizeof(int);
    int* scol   = (int*)ws;    ws += (size_t)NEDGES * sizeof(int);
    int* bsum   = (int*)ws;    ws += 128 * sizeof(int);
    int* bbase  = (int*)ws;    ws += 128 * sizeof(int);

    // 1) conversions + gsum zero
    convert_all<<<784, 256, 0, stream>>>(x,
        (const float*)d_in[3], (const float*)d_in[4], (const float*)d_in[5],
        (const float*)d_in[6], (const float*)d_in[7], (const float*)d_in[8],
        Wb, Hb, gsum);

    // 2) CSR build (cooperative, internal grid.syncs)
    CsrP cp{rows, cols, deg, offs, cursor, scol, bsum, bbase};
    void* cargs[] = { &cp };
    hipLaunchCooperativeKernel((const void*)csr_build, dim3(784), dim3(256),
                               cargs, 0, stream);

    // 3) three GNN layers (proven R7 kernels)
    const int aggGrid  = (NNODES + 15) / 16;
    const int gemmGrid = 784;
    const ushort* hcur = Hb;
    ushort* hnext = Hc;
    for (int l = 0; l < 3; ++l) {
        const ushort* w1 = Wb + (size_t)(2 * l) * DFEAT * DFEAT;
        const ushort* w2 = Wb + (size_t)(2 * l + 1) * DFEAT * DFEAT;
        aggregate_g16<<<aggGrid, 256, 0, stream>>>(hcur, offs, scol, Ab);
        fused_dual_gemm<<<gemmGrid, 256, 0, stream>>>(hcur, Ab, w1, w2, hnext);
        const ushort* tmp = hcur; hcur = hnext; hnext = (ushort*)tmp;
    }

    // 4) pooling + classifier (cooperative)
    PoolP pp{hcur, batch, gsum, Wc, bc, out};
    void* pargs[] = { &pp };
    hipLaunchCooperativeKernel((const void*)pool_coop, dim3(391), dim3(256),
                               pargs, 0, stream);
}

// Round 10
// 315.531 us; speedup vs baseline: 2.5905x; 2.5905x over previous
//
#include <hip/hip_runtime.h>

#define NNODES 100000
#define NEDGES 625000
#define DFEAT  128
#define NGRAPH 256
#define DOUTC  10

typedef __attribute__((ext_vector_type(8))) short bf16x8;
typedef __attribute__((ext_vector_type(4))) float f32x4;
typedef __attribute__((ext_vector_type(8))) ushort ushort8v;

__device__ __forceinline__ ushort f2bf(float f) {
    __bf16 b = (__bf16)f;
    return __builtin_bit_cast(ushort, b);
}
__device__ __forceinline__ float bf2f(ushort u) {
    return __builtin_bit_cast(float, (uint)u << 16);
}

// ---------------------------------------------------------------------------
// convert_all: weights->bf16, x->bf16, zero gsum/deg/counter (one kernel)
// ---------------------------------------------------------------------------
__global__ __launch_bounds__(256) void convert_all(const float* __restrict__ x,
                                                   const float* __restrict__ w0,
                                                   const float* __restrict__ w1,
                                                   const float* __restrict__ w2,
                                                   const float* __restrict__ w3,
                                                   const float* __restrict__ w4,
                                                   const float* __restrict__ w5,
                                                   ushort* __restrict__ Wb,
                                                   ushort* __restrict__ Hb,
                                                   float* __restrict__ gsum,
                                                   int* __restrict__ deg,
                                                   int* __restrict__ counter) {
    const int tid = blockIdx.x * 256 + threadIdx.x;
    const int NT = gridDim.x * 256;
    if (tid == 0) *counter = 0;
    const float* ptrs[6] = {w0, w1, w2, w3, w4, w5};
    for (int i = tid; i < 6 * DFEAT * DFEAT; i += NT) {
        int m = i >> 14, j = i & 16383;
        Wb[i] = f2bf(ptrs[m][j]);
    }
    for (int i = tid; i < NGRAPH * DFEAT; i += NT) gsum[i] = 0.f;
    for (int i = tid; i < NNODES; i += NT) deg[i] = 0;
    const int n8 = NNODES * DFEAT / 8;
    for (int i = tid; i < n8; i += NT) {
        float4 a = *(const float4*)&x[(size_t)i * 8];
        float4 b = *(const float4*)&x[(size_t)i * 8 + 4];
        ushort8v o;
        o[0] = f2bf(a.x); o[1] = f2bf(a.y); o[2] = f2bf(a.z); o[3] = f2bf(a.w);
        o[4] = f2bf(b.x); o[5] = f2bf(b.y); o[6] = f2bf(b.z); o[7] = f2bf(b.w);
        *(ushort8v*)&Hb[(size_t)i * 8] = o;
    }
}

// ---------------------------------------------------------------------------
// CSR build, scan-free: histogram -> per-block alloc -> scatter
// ---------------------------------------------------------------------------
__global__ __launch_bounds__(256) void histo_kernel(const int* __restrict__ rows,
                                                    int* __restrict__ deg) {
    int i = blockIdx.x * 256 + threadIdx.x;
    if (i < NEDGES) atomicAdd(&deg[rows[i]], 1);
}

// Each block: LDS-scan 256 degrees, one atomicAdd allocates the block's range.
// offs[n] = start of node n's range (non-monotonic across blocks — harmless).
__global__ __launch_bounds__(256) void alloc_ranges(const int* __restrict__ deg,
                                                    int* __restrict__ offs,
                                                    int* __restrict__ cursor,
                                                    int* __restrict__ counter) {
    __shared__ int red[256];
    __shared__ int baseSh;
    int t = threadIdx.x;
    int i = blockIdx.x * 256 + t;
    int v = (i < NNODES) ? deg[i] : 0;
    red[t] = v;
    __syncthreads();
    int x = v;
    for (int off = 1; off < 256; off <<= 1) {
        int y = (t >= off) ? red[t - off] : 0;
        __syncthreads();
        x += y;
        red[t] = x;
        __syncthreads();
    }
    if (t == 255) baseSh = atomicAdd(counter, x);   // x = block total
    __syncthreads();
    int pos = baseSh + x - v;                        // exclusive prefix
    if (i < NNODES) { offs[i] = pos; cursor[i] = pos; }
}

__global__ __launch_bounds__(256) void scatter_edges(const int* __restrict__ rows,
                                                     const int* __restrict__ cols,
                                                     int* __restrict__ cursor,
                                                     int* __restrict__ scol) {
    int i = blockIdx.x * 256 + threadIdx.x;
    if (i < NEDGES) {
        int p = atomicAdd(&cursor[rows[i]], 1);
        scol[p] = cols[i];
    }
}

// ---------------------------------------------------------------------------
// Aggregate in H-space: A[n] = sum_{e in [offs[n], offs[n]+deg[n])} H[scol[e]]
// One 16-lane group per node (4 nodes/wave), lane owns 8 features (16 B).
// (R7 body; end bound now offs+deg)
// ---------------------------------------------------------------------------
__global__ __launch_bounds__(256) void aggregate_g16(const ushort* __restrict__ Hb,
                                                     const int* __restrict__ offs,
                                                     const int* __restrict__ deg,
                                                     const int* __restrict__ scol,
                                                     ushort* __restrict__ Ab) {
    int node = blockIdx.x * 16 + (threadIdx.x >> 4);
    int l = threadIdx.x & 15;
    if (node >= NNODES) return;
    int beg = offs[node];
    int end = beg + deg[node];
    float a[8] = {};
    int e = beg;
    for (; e + 2 <= end; e += 2) {
        int c0 = scol[e];
        int c1 = scol[e + 1];
        ushort8v v0 = *(const ushort8v*)&Hb[(size_t)c0 * DFEAT + l * 8];
        ushort8v v1 = *(const ushort8v*)&Hb[(size_t)c1 * DFEAT + l * 8];
#pragma unroll
        for (int j = 0; j < 8; ++j) a[j] += bf2f(v0[j]) + bf2f(v1[j]);
    }
    if (e < end) {
        int c0 = scol[e];
        ushort8v v0 = *(const ushort8v*)&Hb[(size_t)c0 * DFEAT + l * 8];
#pragma unroll
        for (int j = 0; j < 8; ++j) a[j] += bf2f(v0[j]);
    }
    ushort8v o;
#pragma unroll
    for (int j = 0; j < 8; ++j) o[j] = f2bf(a[j]);
    *(ushort8v*)&Ab[(size_t)node * DFEAT + l * 8] = o;
}

// ---------------------------------------------------------------------------
// Fused layer GEMM: H' = relu(H @ W1^T + A @ W2^T)  (identical to R7 — proven)
// ---------------------------------------------------------------------------
__global__ __launch_bounds__(256, 2) void fused_dual_gemm(const ushort* __restrict__ Hin,
                                                          const ushort* __restrict__ Ab,
                                                          const ushort* __restrict__ W1b,
                                                          const ushort* __restrict__ W2b,
                                                          ushort* __restrict__ Hout) {
    int wid = threadIdx.x >> 6;
    int lane = threadIdx.x & 63;
    int l15 = lane & 15, lhi = lane >> 4;
    int half = wid & 1;

    bf16x8 w1[4][4], w2[4][4];
#pragma unroll
    for (int ot = 0; ot < 4; ++ot)
#pragma unroll
        for (int ks = 0; ks < 4; ++ks) {
            int orow = half * 64 + ot * 16 + l15;
            w1[ot][ks] = *(const bf16x8*)&W1b[orow * DFEAT + ks * 32 + lhi * 8];
            w2[ot][ks] = *(const bf16x8*)&W2b[orow * DFEAT + ks * 32 + lhi * 8];
        }

    int team = blockIdx.x * 2 + (wid >> 1);
    const int nteams = gridDim.x * 2;
    const int ntiles = NNODES / 16;              // 6250 exactly

    for (int t = team; t < ntiles; t += nteams) {
        size_t rowOff = (size_t)(t * 16 + l15) * DFEAT;
        bf16x8 hfr[4], afr[4];
#pragma unroll
        for (int ks = 0; ks < 4; ++ks) {
            hfr[ks] = *(const bf16x8*)&Hin[rowOff + ks * 32 + lhi * 8];
            afr[ks] = *(const bf16x8*)&Ab[rowOff + ks * 32 + lhi * 8];
        }
#pragma unroll
        for (int ot = 0; ot < 4; ++ot) {
            f32x4 acc = {};
#pragma unroll
            for (int ks = 0; ks < 4; ++ks)
                acc = __builtin_amdgcn_mfma_f32_16x16x32_bf16(w1[ot][ks], hfr[ks], acc, 0, 0, 0);
#pragma unroll
            for (int ks = 0; ks < 4; ++ks)
                acc = __builtin_amdgcn_mfma_f32_16x16x32_bf16(w2[ot][ks], afr[ks], acc, 0, 0, 0);
            ushort4 p;
            p.x = f2bf(fmaxf(acc.x, 0.f));
            p.y = f2bf(fmaxf(acc.y, 0.f));
            p.z = f2bf(fmaxf(acc.z, 0.f));
            p.w = f2bf(fmaxf(acc.w, 0.f));
            *(ushort4*)&Hout[rowOff + half * 64 + ot * 16 + lhi * 4] = p;
        }
    }
}

// ---------------------------------------------------------------------------
// Pooling phase 1: per-graph feature sums (run-accumulate over sorted batch).
// ---------------------------------------------------------------------------
__global__ __launch_bounds__(256) void pool_partial(const ushort* __restrict__ Hb,
                                                    const int* __restrict__ batch,
                                                    float* __restrict__ gsum) {
    int wave = (blockIdx.x * 256 + threadIdx.x) >> 6;
    int lane = threadIdx.x & 63;
    int base = wave * 64;
    if (base >= NNODES) return;
    int end = min(base + 64, NNODES);
    const uint* Hp = (const uint*)Hb + lane;
    float ax = 0.f, ay = 0.f;
    int gprev = batch[base];
    for (int n = base; n < end; ++n) {
        int g = batch[n];
        if (g != gprev) {
            atomicAdd(&gsum[gprev * DFEAT + lane * 2], ax);
            atomicAdd(&gsum[gprev * DFEAT + lane * 2 + 1], ay);
            ax = 0.f; ay = 0.f; gprev = g;
        }
        uint v = Hp[(size_t)n * 64];
        ax += __builtin_bit_cast(float, v << 16);
        ay += __builtin_bit_cast(float, v & 0xffff0000u);
    }
    atomicAdd(&gsum[gprev * DFEAT + lane * 2], ax);
    atomicAdd(&gsum[gprev * DFEAT + lane * 2 + 1], ay);
}

// ---------------------------------------------------------------------------
// Pooling phase 2: divide by count, classify.
// ---------------------------------------------------------------------------
__global__ __launch_bounds__(128) void pool_classify2(const float* __restrict__ gsum,
                                                      const int* __restrict__ batch,
                                                      const float* __restrict__ Wc,
                                                      const float* __restrict__ bc,
                                                      float* __restrict__ out) {
    int g = blockIdx.x;
    int f = threadIdx.x;
    __shared__ int bounds[2];
    if (f < 2) {
        int target = g + f;
        int lo = 0, hi = NNODES;
        while (lo < hi) {
            int mid = (lo + hi) >> 1;
            if (batch[mid] < target) lo = mid + 1; else hi = mid;
        }
        bounds[f] = lo;
    }
    __syncthreads();
    float cnt = (float)(bounds[1] - bounds[0]);
    float pooled = gsum[g * DFEAT + f] / fmaxf(cnt, 1.0f);

    __shared__ float red[128];
    for (int o = 0; o < DOUTC; ++o) {
        red[f] = pooled * Wc[o * DFEAT + f];
        __syncthreads();
        for (int off = 64; off > 0; off >>= 1) {
            if (f < off) red[f] += red[f + off];
            __syncthreads();
        }
        if (f == 0) out[g * DOUTC + o] = red[0] + bc[o];
        __syncthreads();
    }
}

// ---------------------------------------------------------------------------
extern "C" void kernel_launch(void* const* d_in, const int* in_sizes, int n_in,
                              void* d_out, int out_size, void* d_ws, size_t ws_size,
                              hipStream_t stream) {
    const float* x    = (const float*)d_in[0];
    const int*   ei   = (const int*)d_in[1];
    const int*   batch= (const int*)d_in[2];
    const float* Wc   = (const float*)d_in[9];
    const float* bc   = (const float*)d_in[10];
    float* out = (float*)d_out;

    const int* rows = ei;            // edge_index[0] = dst (segment)
    const int* cols = ei + NEDGES;   // edge_index[1] = src (gather)

    // workspace carve-up
    char* ws = (char*)d_ws;
    ushort* Hb = (ushort*)ws;  ws += (size_t)NNODES * DFEAT * sizeof(ushort);
    ushort* Hc = (ushort*)ws;  ws += (size_t)NNODES * DFEAT * sizeof(ushort);
    ushort* Ab = (ushort*)ws;  ws += (size_t)NNODES * DFEAT * sizeof(ushort);
    ushort* Wb = (ushort*)ws;  ws += (size_t)6 * DFEAT * DFEAT * sizeof(ushort);
    float* gsum = (float*)ws;  ws += (size_t)NGRAPH * DFEAT * sizeof(float);
    int* deg    = (int*)ws;    ws += (size_t)NNODES * sizeof(int);
    int* offs   = (int*)ws;    ws += (size_t)NNODES * sizeof(int);
    int* cursor = (int*)ws;    ws += (size_t)NNODES * sizeof(int);
    int* scol   = (int*)ws;    ws += (size_t)NEDGES * sizeof(int);
    int* counter= (int*)ws;    ws += 64;

    // 1) conversions + zero-init (1 dispatch)
    convert_all<<<784, 256, 0, stream>>>(x,
        (const float*)d_in[3], (const float*)d_in[4], (const float*)d_in[5],
        (const float*)d_in[6], (const float*)d_in[7], (const float*)d_in[8],
        Wb, Hb, gsum, deg, counter);

    // 2) CSR build: histo -> alloc -> scatter (3 dispatches)
    histo_kernel<<<(NEDGES + 255) / 256, 256, 0, stream>>>(rows, deg);
    alloc_ranges<<<(NNODES + 255) / 256, 256, 0, stream>>>(deg, offs, cursor, counter);
    scatter_edges<<<(NEDGES + 255) / 256, 256, 0, stream>>>(rows, cols, cursor, scol);

    // 3) three GNN layers (proven R7 kernels)
    const int aggGrid  = (NNODES + 15) / 16;
    const int gemmGrid = 784;
    const ushort* hcur = Hb;
    ushort* hnext = Hc;
    for (int l = 0; l < 3; ++l) {
        const ushort* w1 = Wb + (size_t)(2 * l) * DFEAT * DFEAT;
        const ushort* w2 = Wb + (size_t)(2 * l + 1) * DFEAT * DFEAT;
        aggregate_g16<<<aggGrid, 256, 0, stream>>>(hcur, offs, deg, scol, Ab);
        fused_dual_gemm<<<gemmGrid, 256, 0, stream>>>(hcur, Ab, w1, w2, hnext);
        const ushort* tmp = hcur; hcur = hnext; hnext = (ushort*)tmp;
    }

    // 4) pooling + classifier (2 dispatches)
    const int poolWaves = (NNODES + 63) / 64;
    pool_partial<<<(poolWaves * 64 + 255) / 256, 256, 0, stream>>>(hcur, batch, gsum);
    pool_classify2<<<NGRAPH, 128, 0, stream>>>(gsum, batch, Wc, bc, out);
}